// Round 4
// baseline (609.831 us; speedup 1.0000x reference)
//
#include <hip/hip_runtime.h>
#include <hip/hip_bf16.h>

// B=64 batch, T=512 enc timesteps, E=1024 enc hidden, D=1024 dec hidden
// ALL inputs/outputs are FLOAT32 (per reference setup_inputs).
#define BB 64
#define TT 512
#define EE 1024
#define DD 1024
// Fused e-proj GEMM: M = T*B = 32768, N = 2E = 2048, K = E = 1024 (bf16 MFMA)
#define BK 64   // k-tile depth

typedef __attribute__((ext_vector_type(8))) short s16x8;   // 8 bf16 MFMA A/B frag
typedef __attribute__((ext_vector_type(4))) float f32x4;   // MFMA C/D frag

#define AS1 __attribute__((address_space(1)))
#define AS3 __attribute__((address_space(3)))

__device__ __forceinline__ float bf2f(unsigned short u) {
    unsigned int x = ((unsigned int)u) << 16;
    return __builtin_bit_cast(float, x);
}
__device__ __forceinline__ unsigned short f2bf(float f) {   // RNE, finite inputs
    unsigned int u = __builtin_bit_cast(unsigned int, f);
    u += 0x7FFF + ((u >> 16) & 1);
    return (unsigned short)(u >> 16);
}
__device__ __forceinline__ float tanh_fast(float x) {
    x = fminf(fmaxf(x, -15.f), 15.f);
    float e = __expf(2.f * x);
    return (e - 1.f) / (e + 1.f);
}

// Tile-order slot for chunk (row 0..127, g 0..7):  [8 bf16 chunks of 16B]
//   slot = (row>>4)*128 + (g>>2)*64 + (g&3)*16 + (row&15)
// Fragment reads are lane-linear: slot = m16*128 + kk*64 + lane -> lane holds
//   A[row=m16*16+(lane&15)][k=kk*32+(lane>>4)*8 ..+8]
__device__ __forceinline__ int tile_slot(int row, int g) {
    return (row >> 4) * 128 + (g >> 2) * 64 + (g & 3) * 16 + (row & 15);
}

// ---------------------------------------------------------------------------
// enc f32 [32768,1024] -> encS bf16 tiled: tile (tm 0..255, tk 0..15) of
// 128 rows x 64 k stored as 1024 chunks in tile_slot order (16 KB/tile).
// grid = (256, 16), block = 256. LDS transpose for coalescing on both ends.
// ---------------------------------------------------------------------------
__global__ __launch_bounds__(256) void conv_encS_kernel(
    const float* __restrict__ enc, unsigned short* __restrict__ encS)
{
    __shared__ short tileL[1024 * 8];   // 16 KB
    const int tm  = blockIdx.x;
    const int tk  = blockIdx.y;
    const int tid = threadIdx.x;

#pragma unroll
    for (int it = 0; it < 4; ++it) {
        int cidx = it * 256 + tid;       // chunk id
        int row  = cidx >> 3;            // 0..127
        int g    = cidx & 7;             // 0..7
        const float* src = enc + (size_t)(tm * 128 + row) * 1024 + tk * 64 + g * 8;
        float4 v0 = ((const float4*)src)[0];
        float4 v1 = ((const float4*)src)[1];
        short c[8];
        c[0] = (short)f2bf(v0.x); c[1] = (short)f2bf(v0.y);
        c[2] = (short)f2bf(v0.z); c[3] = (short)f2bf(v0.w);
        c[4] = (short)f2bf(v1.x); c[5] = (short)f2bf(v1.y);
        c[6] = (short)f2bf(v1.z); c[7] = (short)f2bf(v1.w);
        *(s16x8*)&tileL[tile_slot(row, g) * 8] = *(s16x8*)c;
    }
    __syncthreads();
    unsigned short* dst = encS + ((size_t)tm * 16 + tk) * 8192;
#pragma unroll
    for (int it = 0; it < 4; ++it) {
        int s = it * 256 + tid;
        *(s16x8*)&dst[s * 8] = *(const s16x8*)&tileL[s * 8];
    }
}

// ---------------------------------------------------------------------------
// Wa[:,1024:2048] f32 -> WaS bf16 tiled: tile (tn 0..15, tk 0..15), same
// tile_slot order (rows = f within 128-col tile). grid = (16,16).
// ---------------------------------------------------------------------------
__global__ __launch_bounds__(256) void conv_waS_kernel(
    const float* __restrict__ Wa, unsigned short* __restrict__ WaS)
{
    __shared__ short tileL[1024 * 8];
    const int tn  = blockIdx.x;
    const int tk  = blockIdx.y;
    const int tid = threadIdx.x;

#pragma unroll
    for (int it = 0; it < 4; ++it) {
        int cidx = it * 256 + tid;
        int row  = cidx >> 3;            // f within tile
        int g    = cidx & 7;
        const float* src = Wa + (size_t)(tn * 128 + row) * 2048 + 1024 + tk * 64 + g * 8;
        float4 v0 = ((const float4*)src)[0];
        float4 v1 = ((const float4*)src)[1];
        short c[8];
        c[0] = (short)f2bf(v0.x); c[1] = (short)f2bf(v0.y);
        c[2] = (short)f2bf(v0.z); c[3] = (short)f2bf(v0.w);
        c[4] = (short)f2bf(v1.x); c[5] = (short)f2bf(v1.y);
        c[6] = (short)f2bf(v1.z); c[7] = (short)f2bf(v1.w);
        *(s16x8*)&tileL[tile_slot(row, g) * 8] = *(s16x8*)c;
    }
    __syncthreads();
    unsigned short* dst = WaS + ((size_t)tn * 16 + tk) * 8192;
#pragma unroll
    for (int it = 0; it < 4; ++it) {
        int s = it * 256 + tid;
        *(s16x8*)&dst[s * 8] = *(const s16x8*)&tileL[s * 8];
    }
}

// ---------------------------------------------------------------------------
// hproj[f][b] = hidden[b,:1024] . Wa[f,:1024] + ba[f]   (f-major, f32)
// ---------------------------------------------------------------------------
__global__ __launch_bounds__(256) void hproj_kernel(
    const float* __restrict__ hidden,   // [64,1024]
    const float* __restrict__ Wa,       // [2048,2048]
    const float* __restrict__ ba,       // [2048]
    float* __restrict__ hp)             // [2048*64]
{
    __shared__ float sW[8 * 1024];      // 32 KB
    const int tid  = threadIdx.x;
    const int lane = tid & 63;
    const int wave = tid >> 6;
    const int f0   = blockIdx.x * 8;

#pragma unroll
    for (int i = 0; i < 8; ++i) {
        int idx = i * 256 + tid;
        int fi  = idx >> 8;
        int c4  = idx & 255;
        ((float4*)sW)[idx] = *(const float4*)(Wa + (size_t)(f0 + fi) * 2048 + c4 * 4);
    }
    __syncthreads();

    for (int bi = 0; bi < 16; ++bi) {
        int b = wave * 16 + bi;
        float h[16];
#pragma unroll
        for (int j = 0; j < 16; ++j) h[j] = hidden[b * 1024 + lane + 64 * j];
#pragma unroll
        for (int fi = 0; fi < 8; ++fi) {
            float s = 0.f;
#pragma unroll
            for (int j = 0; j < 16; ++j) s += h[j] * sW[fi * 1024 + lane + 64 * j];
#pragma unroll
            for (int m = 32; m; m >>= 1) s += __shfl_xor(s, m);
            if (lane == 0) hp[(f0 + fi) * 64 + b] = s + ba[f0 + fi];
        }
    }
}

// ---------------------------------------------------------------------------
// Fused e_proj GEMM (bf16 MFMA) + tanh + w2-dot -> scores
// 256x256 tile, 8 waves (2M x 4N), BK=64, phase-split schedule (round-2
// structure, best measured: 201 us). Stage pairs for tile kt+1 are spread
// across tile kt's 4 phases; vmcnt(0) wait at tile top.
// grid = 1024 (XCD-swizzled, bn-fast), block = 512.
// ---------------------------------------------------------------------------
__global__ __launch_bounds__(512, 2) void gemm_scores(
    const unsigned short* __restrict__ encS,  // tiled bf16 (ws), 256 x 16 tiles
    const unsigned short* __restrict__ WaS,   // tiled bf16 (ws), 16 x 16 tiles
    const float* __restrict__ hp,             // [2048*64] f32, f-major
    const float* __restrict__ w2,             // [2048] f32
    float* __restrict__ scores)               // [64*512] f32, zeroed
{
    __shared__ short sA[2][2][8192];   // [buf][mt] 16KB pre-swizzled tiles (64 KB)
    __shared__ short sB[2][2][8192];   // [buf][nt]                         (64 KB)
    __shared__ float rowAcc[256];

    const int tid  = threadIdx.x;
    // XCD-aware bijective swizzle: 1024 blocks, 8 XCDs, 128 w's each; bn-fast.
    const int bid  = blockIdx.x;
    const int w    = (bid & 7) * 128 + (bid >> 3);
    const int bm   = w >> 3;          // 0..127  (M/256)
    const int bn   = w & 7;           // 0..7    (N/256)
    const int lane = tid & 63;
    const int wave = tid >> 6;        // 0..7
    const int wm   = wave >> 2;       // 0..1  (M half)
    const int wn   = wave & 3;        // 0..3  (N quarter)
    const int c    = lane & 15;
    const int quad = lane >> 4;
    const int ntile = wn >> 1;          // which 128-col B tile this wave reads
    const int nrow0 = (wn & 1) * 4;     // f16-row base within that tile

    f32x4 acc[8][4];
#pragma unroll
    for (int m = 0; m < 8; ++m)
#pragma unroll
        for (int n = 0; n < 4; ++n)
#pragma unroll
            for (int r = 0; r < 4; ++r) acc[m][n][r] = 0.f;

    const unsigned short* aT = encS + ((size_t)(bm * 2) * 16) * 8192; // +(mt*16+kt)*8192
    const unsigned short* bT = WaS  + ((size_t)(bn * 2) * 16) * 8192; // +(nt*16+kt)*8192

    // issue 2 of the 8 stage loads for K-tile kt into buffer nb (phase p owns pair p)
    auto STAGE_PAIR = [&](int kt, int nb, int p) {
        if (p < 2) {
            const unsigned short* src = aT + ((size_t)(p * 16 + kt)) * 8192;
            __builtin_amdgcn_global_load_lds(
                (const AS1 void*)(src + tid * 8),
                (AS3 void*)&sA[nb][p][tid * 8], 16, 0, 0);
            __builtin_amdgcn_global_load_lds(
                (const AS1 void*)(src + (512 + tid) * 8),
                (AS3 void*)&sA[nb][p][(512 + tid) * 8], 16, 0, 0);
        } else {
            const int nt = p - 2;
            const unsigned short* src = bT + ((size_t)(nt * 16 + kt)) * 8192;
            __builtin_amdgcn_global_load_lds(
                (const AS1 void*)(src + tid * 8),
                (AS3 void*)&sB[nb][nt][tid * 8], 16, 0, 0);
            __builtin_amdgcn_global_load_lds(
                (const AS1 void*)(src + (512 + tid) * 8),
                (AS3 void*)&sB[nb][nt][(512 + tid) * 8], 16, 0, 0);
        }
    };

    // prologue: issue all 8 loads for tile 0 into buffer 0
#pragma unroll
    for (int p = 0; p < 4; ++p) STAGE_PAIR(0, 0, p);

    for (int kt = 0; kt < 16; ++kt) {
        const int cur = kt & 1;
        // wait own loads for tile kt (issued one K-tile ago), then sync all waves
        asm volatile("s_waitcnt vmcnt(0)" ::: "memory");
        __builtin_amdgcn_s_barrier();
        __builtin_amdgcn_sched_barrier(0);
        const bool pf = (kt < 15);

        s16x8 bF[2][4];   // [kk][n], live across all 4 phases
#pragma unroll
        for (int p = 0; p < 4; ++p) {
            if (p == 0) {
#pragma unroll
                for (int n = 0; n < 4; ++n)
#pragma unroll
                    for (int kk = 0; kk < 2; ++kk)
                        bF[kk][n] = *(const s16x8*)
                            &sB[cur][ntile][((nrow0 + n) * 128 + kk * 64 + lane) * 8];
            }
            s16x8 aF[2][2];   // [j][kk] for m = 2p+j
#pragma unroll
            for (int j = 0; j < 2; ++j)
#pragma unroll
                for (int kk = 0; kk < 2; ++kk)
                    aF[j][kk] = *(const s16x8*)
                        &sA[cur][wm][((2 * p + j) * 128 + kk * 64 + lane) * 8];

            if (pf) STAGE_PAIR(kt + 1, cur ^ 1, p);

            __builtin_amdgcn_sched_barrier(0);
            __builtin_amdgcn_s_barrier();
            __builtin_amdgcn_s_setprio(1);
#pragma unroll
            for (int j = 0; j < 2; ++j)
#pragma unroll
                for (int kk = 0; kk < 2; ++kk)
#pragma unroll
                    for (int n = 0; n < 4; ++n)
                        acc[2 * p + j][n] = __builtin_amdgcn_mfma_f32_16x16x32_bf16(
                            aF[j][kk], bF[kk][n], acc[2 * p + j][n], 0, 0, 0);
            __builtin_amdgcn_s_setprio(0);
            __builtin_amdgcn_sched_barrier(0);
            if (p < 3) __builtin_amdgcn_s_barrier();
        }
    }

    // Epilogue: scores_row += sum_f tanh(C + hp) * w2 over this block's 256 cols.
    __syncthreads();
    if (tid < 256) rowAcc[tid] = 0.f;
    __syncthreads();

    float w2v[4];
#pragma unroll
    for (int n = 0; n < 4; ++n) w2v[n] = w2[bn * 256 + wn * 64 + n * 16 + c];

#pragma unroll
    for (int m = 0; m < 8; ++m) {
        int lrow0 = wm * 128 + m * 16 + quad * 4;       // local row, 4-aligned
        int b0    = lrow0 & 63;                          // batch base (bm*256 % 64 == 0)
        f32x4 hp4[4];
#pragma unroll
        for (int n = 0; n < 4; ++n)
            hp4[n] = *(const f32x4*)&hp[(bn * 256 + wn * 64 + n * 16 + c) * 64 + b0];
#pragma unroll
        for (int r = 0; r < 4; ++r) {
            float s = 0.f;
#pragma unroll
            for (int n = 0; n < 4; ++n)
                s += tanh_fast(acc[m][n][r] + hp4[n][r]) * w2v[n];
            s += __shfl_xor(s, 1);
            s += __shfl_xor(s, 2);
            s += __shfl_xor(s, 4);
            s += __shfl_xor(s, 8);
            if (c == 0) atomicAdd(&rowAcc[lrow0 + r], s);
        }
    }
    __syncthreads();
    if (tid < 256) {
        int b = tid & 63;
        int t = bm * 4 + (tid >> 6);
        atomicAdd(&scores[b * TT + t], rowAcc[tid]);
    }
}

// ---------------------------------------------------------------------------
// Softmax over T per batch row, in-place on scores [64][512]
// ---------------------------------------------------------------------------
__global__ __launch_bounds__(256) void softmax_kernel(float* __restrict__ scores)
{
    __shared__ float wmax[4];
    __shared__ float wsum[4];
    const int b   = blockIdx.x;
    const int tid = threadIdx.x;
    float* row = scores + b * TT;

    float v0 = row[tid], v1 = row[tid + 256];
    float m = fmaxf(v0, v1);
#pragma unroll
    for (int s = 32; s; s >>= 1) m = fmaxf(m, __shfl_xor(m, s));
    if ((tid & 63) == 0) wmax[tid >> 6] = m;
    __syncthreads();
    m = fmaxf(fmaxf(wmax[0], wmax[1]), fmaxf(wmax[2], wmax[3]));

    float e0 = __expf(v0 - m), e1 = __expf(v1 - m);
    float s = e0 + e1;
#pragma unroll
    for (int t = 32; t; t >>= 1) s += __shfl_xor(s, t);
    if ((tid & 63) == 0) wsum[tid >> 6] = s;
    __syncthreads();
    float inv = 1.f / (wsum[0] + wsum[1] + wsum[2] + wsum[3]);
    row[tid]       = e0 * inv;
    row[tid + 256] = e1 * inv;
}

// ---------------------------------------------------------------------------
// applied partials from ORIGINAL f32 enc (coalesced 4KB rows):
// part[tc][b][e] = sum_{t in chunk tc} w[b,t]*enc[t,b,e]
// grid = (16 tc, 64 b), block = 256: 128 e-owners x 2 t-halves
// ---------------------------------------------------------------------------
__global__ __launch_bounds__(256) void applied_part_kernel(
    const float* __restrict__ enc,            // [T,B,E] f32
    const float* __restrict__ w,              // [64,512] weights
    float* __restrict__ part)                 // [16][64][1024]
{
    __shared__ float red[128 * 8];
    const int tc  = blockIdx.x;
    const int b   = blockIdx.y;
    const int tid = threadIdx.x;
    const int eo  = tid & 127;
    const int th  = tid >> 7;
    const int e0  = eo * 8;

    float a[8];
#pragma unroll
    for (int j = 0; j < 8; ++j) a[j] = 0.f;

    for (int it = 0; it < 16; ++it) {
        int t = tc * 32 + th * 16 + it;
        float wt = w[b * TT + t];
        const float* src = enc + ((size_t)(t * BB + b)) * EE + e0;
        float4 v0 = ((const float4*)src)[0];
        float4 v1 = ((const float4*)src)[1];
        a[0] += wt * v0.x; a[1] += wt * v0.y; a[2] += wt * v0.z; a[3] += wt * v0.w;
        a[4] += wt * v1.x; a[5] += wt * v1.y; a[6] += wt * v1.z; a[7] += wt * v1.w;
    }
    if (th == 1) {
#pragma unroll
        for (int j = 0; j < 8; ++j) red[eo * 8 + j] = a[j];
    }
    __syncthreads();
    if (th == 0) {
        float* dst = part + ((size_t)tc * 64 + b) * 1024 + e0;
#pragma unroll
        for (int j = 0; j < 8; ++j) dst[j] = a[j] + red[eo * 8 + j];
    }
}

// reduce 16 partials -> applied (output 1, f32) at out+65536
__global__ __launch_bounds__(256) void applied_reduce_kernel(
    const float* __restrict__ part, float* __restrict__ out_applied)
{
    int idx = blockIdx.x * 256 + threadIdx.x;
    float s = 0.f;
#pragma unroll
    for (int tc = 0; tc < 16; ++tc) s += part[tc * 65536 + idx];
    out_applied[idx] = s;
}

// ---------------------------------------------------------------------------
// out[b,d] = tanh(dec[b].Wc[d,:1024] + applied[b].Wc[d,1024:] + bc[d])
// Register-tiled: each wave computes an 8d x 8b output tile, so each Wc /
// comb element loaded once serves 8 FMAs in registers. Traffic: Wc 64KB +
// comb 64KB per wave x 1024 waves = 128 MB total (vs 768 MB for the
// wave-per-(d,b) version). grid = 256 blocks x 4 waves.
// ---------------------------------------------------------------------------
__global__ __launch_bounds__(256) void combine_kernel(
    const float* __restrict__ dec,       // [64,1024]
    const float* applied,                // [64,1024] (= out+65536)
    const float* __restrict__ Wc,        // [1024,2048]
    const float* __restrict__ bc,        // [1024]
    float* out0)                         // first 65536 of d_out
{
    const int gw   = blockIdx.x * 4 + (threadIdx.x >> 6);  // 0..1023
    const int lane = threadIdx.x & 63;
    const int d0   = (gw >> 3) * 8;      // 128 d-groups
    const int b0   = (gw & 7) * 8;       // 8 b-groups

    float acc[8][8];
#pragma unroll
    for (int dd = 0; dd < 8; ++dd)
#pragma unroll
        for (int bb = 0; bb < 8; ++bb) acc[dd][bb] = 0.f;

#pragma unroll
    for (int j = 0; j < 8; ++j) {
        float4 wv[8];
#pragma unroll
        for (int dd = 0; dd < 8; ++dd)
            wv[dd] = ((const float4*)(Wc + (size_t)(d0 + dd) * 2048))[j * 64 + lane];
        float4 cv[8];
        if (j < 4) {
#pragma unroll
            for (int bb = 0; bb < 8; ++bb)
                cv[bb] = ((const float4*)(dec + (size_t)(b0 + bb) * 1024))[j * 64 + lane];
        } else {
#pragma unroll
            for (int bb = 0; bb < 8; ++bb)
                cv[bb] = ((const float4*)(applied + (size_t)(b0 + bb) * 1024))[(j - 4) * 64 + lane];
        }
#pragma unroll
        for (int dd = 0; dd < 8; ++dd)
#pragma unroll
            for (int bb = 0; bb < 8; ++bb)
                acc[dd][bb] += wv[dd].x * cv[bb].x + wv[dd].y * cv[bb].y
                             + wv[dd].z * cv[bb].z + wv[dd].w * cv[bb].w;
    }

#pragma unroll
    for (int dd = 0; dd < 8; ++dd) {
#pragma unroll
        for (int bb = 0; bb < 8; ++bb) {
            float s = acc[dd][bb];
#pragma unroll
            for (int m = 32; m; m >>= 1) s += __shfl_xor(s, m);
            if (lane == 0)
                out0[(size_t)(b0 + bb) * DD + d0 + dd] = tanh_fast(s + bc[d0 + dd]);
        }
    }
}

// ---------------------------------------------------------------------------
extern "C" void kernel_launch(void* const* d_in, const int* in_sizes, int n_in,
                              void* d_out, int out_size, void* d_ws, size_t ws_size,
                              hipStream_t stream) {
    const float* hidden = (const float*)d_in[0]; // [64,1024]
    const float* dec    = (const float*)d_in[1]; // [64,1024]
    const float* enc    = (const float*)d_in[2]; // [512,64,1024]
    const float* Wa     = (const float*)d_in[3]; // [2048,2048]
    const float* ba     = (const float*)d_in[4]; // [2048]
    const float* w2     = (const float*)d_in[5]; // [2048]
    // d_in[6] = b2: uniform shift of scores -> softmax-invariant, unused.
    const float* Wc     = (const float*)d_in[7]; // [1024,2048]
    const float* bc     = (const float*)d_in[8]; // [1024]
    float* out = (float*)d_out;                  // [64*1024 out | 64*1024 applied]

    unsigned short* encS = (unsigned short*)d_ws;               // 33554432 bf16 (tiled)
    unsigned short* WaS  = encS + (size_t)33554432;             //  2097152 bf16 (tiled)
    float* hp     = (float*)(WaS + (size_t)2097152);            //   131072 f32
    float* scores = hp + 131072;                                //    32768 f32
    float* part   = scores + 32768;                             //  1048576 f32

    hipMemsetAsync(scores, 0, BB * TT * sizeof(float), stream);
    dim3 gc(256, 16);
    conv_encS_kernel<<<gc, 256, 0, stream>>>(enc, encS);
    dim3 gw(16, 16);
    conv_waS_kernel<<<gw, 256, 0, stream>>>(Wa, WaS);
    hproj_kernel<<<256, 256, 0, stream>>>(hidden, Wa, ba, hp);
    gemm_scores<<<1024, 512, 0, stream>>>(encS, WaS, hp, w2, scores);
    softmax_kernel<<<BB, 256, 0, stream>>>(scores);
    dim3 g3(16, 64);
    applied_part_kernel<<<g3, 256, 0, stream>>>(enc, scores, part);
    applied_reduce_kernel<<<256, 256, 0, stream>>>(part, out + BB * DD);
    combine_kernel<<<256, 256, 0, stream>>>(dec, out + BB * DD, Wc, bc, out);
}

// Round 5
// 582.239 us; speedup vs baseline: 1.0474x; 1.0474x over previous
//
#include <hip/hip_runtime.h>
#include <hip/hip_bf16.h>

// B=64 batch, T=512 enc timesteps, E=1024 enc hidden, D=1024 dec hidden
// ALL inputs/outputs are FLOAT32 (per reference setup_inputs).
#define BB 64
#define TT 512
#define EE 1024
#define DD 1024
// Fused e-proj GEMM: M = T*B = 32768, N = 2E = 2048, K = E = 1024 (bf16 MFMA)
#define BK 64   // k-tile depth

typedef __attribute__((ext_vector_type(8))) short s16x8;   // 8 bf16 MFMA A/B frag
typedef __attribute__((ext_vector_type(4))) float f32x4;   // MFMA C/D frag

#define AS1 __attribute__((address_space(1)))
#define AS3 __attribute__((address_space(3)))

__device__ __forceinline__ float bf2f(unsigned short u) {
    unsigned int x = ((unsigned int)u) << 16;
    return __builtin_bit_cast(float, x);
}
__device__ __forceinline__ unsigned short f2bf(float f) {   // RNE, finite inputs
    unsigned int u = __builtin_bit_cast(unsigned int, f);
    u += 0x7FFF + ((u >> 16) & 1);
    return (unsigned short)(u >> 16);
}
__device__ __forceinline__ float tanh_fast(float x) {
    x = fminf(fmaxf(x, -15.f), 15.f);
    float e = __expf(2.f * x);
    return (e - 1.f) / (e + 1.f);
}

// Tile-order slot for chunk (row 0..127, g 0..7):  [8 bf16 chunks of 16B]
//   slot = (row>>4)*128 + (g>>2)*64 + (g&3)*16 + (row&15)
// Fragment reads are lane-linear: slot = m16*128 + kk*64 + lane -> lane holds
//   A[row=m16*16+(lane&15)][k=kk*32+(lane>>4)*8 ..+8]
__device__ __forceinline__ int tile_slot(int row, int g) {
    return (row >> 4) * 128 + (g >> 2) * 64 + (g & 3) * 16 + (row & 15);
}

// ---------------------------------------------------------------------------
// enc f32 [32768,1024] -> encS bf16 tiled: tile (tm 0..255, tk 0..15) of
// 128 rows x 64 k stored as 1024 chunks in tile_slot order (16 KB/tile).
// grid = (256, 16), block = 256. LDS transpose for coalescing on both ends.
// ---------------------------------------------------------------------------
__global__ __launch_bounds__(256) void conv_encS_kernel(
    const float* __restrict__ enc, unsigned short* __restrict__ encS)
{
    __shared__ short tileL[1024 * 8];   // 16 KB
    const int tm  = blockIdx.x;
    const int tk  = blockIdx.y;
    const int tid = threadIdx.x;

#pragma unroll
    for (int it = 0; it < 4; ++it) {
        int cidx = it * 256 + tid;       // chunk id
        int row  = cidx >> 3;            // 0..127
        int g    = cidx & 7;             // 0..7
        const float* src = enc + (size_t)(tm * 128 + row) * 1024 + tk * 64 + g * 8;
        float4 v0 = ((const float4*)src)[0];
        float4 v1 = ((const float4*)src)[1];
        short c[8];
        c[0] = (short)f2bf(v0.x); c[1] = (short)f2bf(v0.y);
        c[2] = (short)f2bf(v0.z); c[3] = (short)f2bf(v0.w);
        c[4] = (short)f2bf(v1.x); c[5] = (short)f2bf(v1.y);
        c[6] = (short)f2bf(v1.z); c[7] = (short)f2bf(v1.w);
        *(s16x8*)&tileL[tile_slot(row, g) * 8] = *(s16x8*)c;
    }
    __syncthreads();
    unsigned short* dst = encS + ((size_t)tm * 16 + tk) * 8192;
#pragma unroll
    for (int it = 0; it < 4; ++it) {
        int s = it * 256 + tid;
        *(s16x8*)&dst[s * 8] = *(const s16x8*)&tileL[s * 8];
    }
}

// ---------------------------------------------------------------------------
// Wa[:,1024:2048] f32 -> WaS bf16 tiled: tile (tn 0..15, tk 0..15), same
// tile_slot order (rows = f within 128-col tile). grid = (16,16).
// ---------------------------------------------------------------------------
__global__ __launch_bounds__(256) void conv_waS_kernel(
    const float* __restrict__ Wa, unsigned short* __restrict__ WaS)
{
    __shared__ short tileL[1024 * 8];
    const int tn  = blockIdx.x;
    const int tk  = blockIdx.y;
    const int tid = threadIdx.x;

#pragma unroll
    for (int it = 0; it < 4; ++it) {
        int cidx = it * 256 + tid;
        int row  = cidx >> 3;            // f within tile
        int g    = cidx & 7;
        const float* src = Wa + (size_t)(tn * 128 + row) * 2048 + 1024 + tk * 64 + g * 8;
        float4 v0 = ((const float4*)src)[0];
        float4 v1 = ((const float4*)src)[1];
        short c[8];
        c[0] = (short)f2bf(v0.x); c[1] = (short)f2bf(v0.y);
        c[2] = (short)f2bf(v0.z); c[3] = (short)f2bf(v0.w);
        c[4] = (short)f2bf(v1.x); c[5] = (short)f2bf(v1.y);
        c[6] = (short)f2bf(v1.z); c[7] = (short)f2bf(v1.w);
        *(s16x8*)&tileL[tile_slot(row, g) * 8] = *(s16x8*)c;
    }
    __syncthreads();
    unsigned short* dst = WaS + ((size_t)tn * 16 + tk) * 8192;
#pragma unroll
    for (int it = 0; it < 4; ++it) {
        int s = it * 256 + tid;
        *(s16x8*)&dst[s * 8] = *(const s16x8*)&tileL[s * 8];
    }
}

// ---------------------------------------------------------------------------
// hproj[f][b] = hidden[b,:1024] . Wa[f,:1024] + ba[f]   (f-major, f32)
// ---------------------------------------------------------------------------
__global__ __launch_bounds__(256) void hproj_kernel(
    const float* __restrict__ hidden,   // [64,1024]
    const float* __restrict__ Wa,       // [2048,2048]
    const float* __restrict__ ba,       // [2048]
    float* __restrict__ hp)             // [2048*64]
{
    __shared__ float sW[8 * 1024];      // 32 KB
    const int tid  = threadIdx.x;
    const int lane = tid & 63;
    const int wave = tid >> 6;
    const int f0   = blockIdx.x * 8;

#pragma unroll
    for (int i = 0; i < 8; ++i) {
        int idx = i * 256 + tid;
        int fi  = idx >> 8;
        int c4  = idx & 255;
        ((float4*)sW)[idx] = *(const float4*)(Wa + (size_t)(f0 + fi) * 2048 + c4 * 4);
    }
    __syncthreads();

    for (int bi = 0; bi < 16; ++bi) {
        int b = wave * 16 + bi;
        float h[16];
#pragma unroll
        for (int j = 0; j < 16; ++j) h[j] = hidden[b * 1024 + lane + 64 * j];
#pragma unroll
        for (int fi = 0; fi < 8; ++fi) {
            float s = 0.f;
#pragma unroll
            for (int j = 0; j < 16; ++j) s += h[j] * sW[fi * 1024 + lane + 64 * j];
#pragma unroll
            for (int m = 32; m; m >>= 1) s += __shfl_xor(s, m);
            if (lane == 0) hp[(f0 + fi) * 64 + b] = s + ba[f0 + fi];
        }
    }
}

// ---------------------------------------------------------------------------
// Fused e_proj GEMM (bf16 MFMA) + tanh + w2-dot -> scores
// 256x256 tile, 8 waves (2M x 4N), BK=64, 4-phase schedule with COUNTED
// vmcnt waits (T4): stage order per K-tile is B0,B1 (phases 0,1) then
// A-h0s (phase 2), A-h1s (phase 3). Phases 0-1 read A rows 0-63 (h0),
// phases 2-3 read rows 64-127 (h1), so:
//   phase0 top: s_waitcnt vmcnt(2)  (needs B+A-h0; A-h1 pair stays in flight)
//   phase2 top: s_waitcnt vmcnt(4)  (needs A-h1; 4 newer kt+2 loads in flight)
// Main loop NEVER drains vmcnt to 0 -- every load gets 3-4 phases of cover.
// grid = 1024 (XCD-swizzled, bn-fast), block = 512.
// ---------------------------------------------------------------------------
__global__ __launch_bounds__(512, 2) void gemm_scores(
    const unsigned short* __restrict__ encS,  // tiled bf16 (ws), 256 x 16 tiles
    const unsigned short* __restrict__ WaS,   // tiled bf16 (ws), 16 x 16 tiles
    const float* __restrict__ hp,             // [2048*64] f32, f-major
    const float* __restrict__ w2,             // [2048] f32
    float* __restrict__ scores)               // [64*512] f32, zeroed
{
    __shared__ short sA[2][2][8192];   // [buf][mt] 16KB pre-swizzled tiles (64 KB)
    __shared__ short sB[2][2][8192];   // [buf][nt]                         (64 KB)
    __shared__ float rowAcc[256];

    const int tid  = threadIdx.x;
    // XCD-aware bijective swizzle: 1024 blocks, 8 XCDs, 128 w's each; bn-fast.
    const int bid  = blockIdx.x;
    const int w    = (bid & 7) * 128 + (bid >> 3);
    const int bm   = w >> 3;          // 0..127  (M/256)
    const int bn   = w & 7;           // 0..7    (N/256)
    const int lane = tid & 63;
    const int wave = tid >> 6;        // 0..7
    const int wm   = wave >> 2;       // 0..1  (M half)
    const int wn   = wave & 3;        // 0..3  (N quarter)
    const int c    = lane & 15;
    const int quad = lane >> 4;
    const int ntile = wn >> 1;          // which 128-col B tile this wave reads
    const int nrow0 = (wn & 1) * 4;     // f16-row base within that tile

    f32x4 acc[8][4];
#pragma unroll
    for (int m = 0; m < 8; ++m)
#pragma unroll
        for (int n = 0; n < 4; ++n)
#pragma unroll
            for (int r = 0; r < 4; ++r) acc[m][n][r] = 0.f;

    const unsigned short* aT = encS + ((size_t)(bm * 2) * 16) * 8192; // +(mt*16+kt)*8192
    const unsigned short* bT = WaS  + ((size_t)(bn * 2) * 16) * 8192; // +(nt*16+kt)*8192

    // Stage pair p for K-tile kt into buffer nb. ISSUE ORDER (per thread):
    //   p=0: B0 (both halves)   p=1: B1 (both halves)
    //   p=2: A0-h0, A1-h0       p=3: A0-h1, A1-h1
    auto STAGE_PAIR = [&](int kt, int nb, int p) {
        if (p < 2) {
            const unsigned short* src = bT + ((size_t)(p * 16 + kt)) * 8192;
            __builtin_amdgcn_global_load_lds(
                (const AS1 void*)(src + tid * 8),
                (AS3 void*)&sB[nb][p][tid * 8], 16, 0, 0);
            __builtin_amdgcn_global_load_lds(
                (const AS1 void*)(src + (512 + tid) * 8),
                (AS3 void*)&sB[nb][p][(512 + tid) * 8], 16, 0, 0);
        } else {
            const int h = (p - 2) * 512;   // half: slots 0-511 or 512-1023
            const unsigned short* s0 = aT + ((size_t)kt) * 8192;
            const unsigned short* s1 = aT + ((size_t)(16 + kt)) * 8192;
            __builtin_amdgcn_global_load_lds(
                (const AS1 void*)(s0 + (h + tid) * 8),
                (AS3 void*)&sA[nb][0][(h + tid) * 8], 16, 0, 0);
            __builtin_amdgcn_global_load_lds(
                (const AS1 void*)(s1 + (h + tid) * 8),
                (AS3 void*)&sA[nb][1][(h + tid) * 8], 16, 0, 0);
        }
    };

    // prologue: issue all 8 loads for tile 0 into buffer 0 (order L0..L7)
#pragma unroll
    for (int p = 0; p < 4; ++p) STAGE_PAIR(0, 0, p);

    for (int kt = 0; kt < 16; ++kt) {
        const int cur = kt & 1;
        const bool pf = (kt < 15);

        s16x8 bF[2][4];   // [kk][n], live across all 4 phases
#pragma unroll
        for (int p = 0; p < 4; ++p) {
            if (p == 0) {
                // need L0-L5 of tile kt (B both + A h0); allow A-h1 in flight
                asm volatile("s_waitcnt vmcnt(2)" ::: "memory");
                __builtin_amdgcn_sched_barrier(0);
                __builtin_amdgcn_s_barrier();
            } else if (p == 2) {
                // need L6,L7 of tile kt (A h1); allow kt+1's L0-L3 in flight
                if (pf) asm volatile("s_waitcnt vmcnt(4)" ::: "memory");
                else    asm volatile("s_waitcnt vmcnt(0)" ::: "memory");
                __builtin_amdgcn_sched_barrier(0);
                __builtin_amdgcn_s_barrier();
            }

            if (p == 0) {
#pragma unroll
                for (int n = 0; n < 4; ++n)
#pragma unroll
                    for (int kk = 0; kk < 2; ++kk)
                        bF[kk][n] = *(const s16x8*)
                            &sB[cur][ntile][((nrow0 + n) * 128 + kk * 64 + lane) * 8];
            }
            s16x8 aF[2][2];   // [j][kk] for m = 2p+j  (phase p reads rows 32p..32p+31)
#pragma unroll
            for (int j = 0; j < 2; ++j)
#pragma unroll
                for (int kk = 0; kk < 2; ++kk)
                    aF[j][kk] = *(const s16x8*)
                        &sA[cur][wm][((2 * p + j) * 128 + kk * 64 + lane) * 8];

            if (pf) STAGE_PAIR(kt + 1, cur ^ 1, p);

            __builtin_amdgcn_sched_barrier(0);
            __builtin_amdgcn_s_barrier();
            __builtin_amdgcn_s_setprio(1);
#pragma unroll
            for (int j = 0; j < 2; ++j)
#pragma unroll
                for (int kk = 0; kk < 2; ++kk)
#pragma unroll
                    for (int n = 0; n < 4; ++n)
                        acc[2 * p + j][n] = __builtin_amdgcn_mfma_f32_16x16x32_bf16(
                            aF[j][kk], bF[kk][n], acc[2 * p + j][n], 0, 0, 0);
            __builtin_amdgcn_s_setprio(0);
            __builtin_amdgcn_sched_barrier(0);
        }
    }

    // Epilogue: scores_row += sum_f tanh(C + hp) * w2 over this block's 256 cols.
    __syncthreads();
    if (tid < 256) rowAcc[tid] = 0.f;
    __syncthreads();

    float w2v[4];
#pragma unroll
    for (int n = 0; n < 4; ++n) w2v[n] = w2[bn * 256 + wn * 64 + n * 16 + c];

#pragma unroll
    for (int m = 0; m < 8; ++m) {
        int lrow0 = wm * 128 + m * 16 + quad * 4;       // local row, 4-aligned
        int b0    = lrow0 & 63;                          // batch base (bm*256 % 64 == 0)
        f32x4 hp4[4];
#pragma unroll
        for (int n = 0; n < 4; ++n)
            hp4[n] = *(const f32x4*)&hp[(bn * 256 + wn * 64 + n * 16 + c) * 64 + b0];
#pragma unroll
        for (int r = 0; r < 4; ++r) {
            float s = 0.f;
#pragma unroll
            for (int n = 0; n < 4; ++n)
                s += tanh_fast(acc[m][n][r] + hp4[n][r]) * w2v[n];
            s += __shfl_xor(s, 1);
            s += __shfl_xor(s, 2);
            s += __shfl_xor(s, 4);
            s += __shfl_xor(s, 8);
            if (c == 0) atomicAdd(&rowAcc[lrow0 + r], s);
        }
    }
    __syncthreads();
    if (tid < 256) {
        int b = tid & 63;
        int t = bm * 4 + (tid >> 6);
        atomicAdd(&scores[b * TT + t], rowAcc[tid]);
    }
}

// ---------------------------------------------------------------------------
// Softmax over T per batch row, in-place on scores [64][512]
// ---------------------------------------------------------------------------
__global__ __launch_bounds__(256) void softmax_kernel(float* __restrict__ scores)
{
    __shared__ float wmax[4];
    __shared__ float wsum[4];
    const int b   = blockIdx.x;
    const int tid = threadIdx.x;
    float* row = scores + b * TT;

    float v0 = row[tid], v1 = row[tid + 256];
    float m = fmaxf(v0, v1);
#pragma unroll
    for (int s = 32; s; s >>= 1) m = fmaxf(m, __shfl_xor(m, s));
    if ((tid & 63) == 0) wmax[tid >> 6] = m;
    __syncthreads();
    m = fmaxf(fmaxf(wmax[0], wmax[1]), fmaxf(wmax[2], wmax[3]));

    float e0 = __expf(v0 - m), e1 = __expf(v1 - m);
    float s = e0 + e1;
#pragma unroll
    for (int t = 32; t; t >>= 1) s += __shfl_xor(s, t);
    if ((tid & 63) == 0) wsum[tid >> 6] = s;
    __syncthreads();
    float inv = 1.f / (wsum[0] + wsum[1] + wsum[2] + wsum[3]);
    row[tid]       = e0 * inv;
    row[tid + 256] = e1 * inv;
}

// ---------------------------------------------------------------------------
// applied partials from ORIGINAL f32 enc (coalesced 4KB rows):
// part[tc][b][e] = sum_{t in chunk tc} w[b,t]*enc[t,b,e]
// grid = (16 tc, 64 b), block = 256: 128 e-owners x 2 t-halves
// ---------------------------------------------------------------------------
__global__ __launch_bounds__(256) void applied_part_kernel(
    const float* __restrict__ enc,            // [T,B,E] f32
    const float* __restrict__ w,              // [64,512] weights
    float* __restrict__ part)                 // [16][64][1024]
{
    __shared__ float red[128 * 8];
    const int tc  = blockIdx.x;
    const int b   = blockIdx.y;
    const int tid = threadIdx.x;
    const int eo  = tid & 127;
    const int th  = tid >> 7;
    const int e0  = eo * 8;

    float a[8];
#pragma unroll
    for (int j = 0; j < 8; ++j) a[j] = 0.f;

    for (int it = 0; it < 16; ++it) {
        int t = tc * 32 + th * 16 + it;
        float wt = w[b * TT + t];
        const float* src = enc + ((size_t)(t * BB + b)) * EE + e0;
        float4 v0 = ((const float4*)src)[0];
        float4 v1 = ((const float4*)src)[1];
        a[0] += wt * v0.x; a[1] += wt * v0.y; a[2] += wt * v0.z; a[3] += wt * v0.w;
        a[4] += wt * v1.x; a[5] += wt * v1.y; a[6] += wt * v1.z; a[7] += wt * v1.w;
    }
    if (th == 1) {
#pragma unroll
        for (int j = 0; j < 8; ++j) red[eo * 8 + j] = a[j];
    }
    __syncthreads();
    if (th == 0) {
        float* dst = part + ((size_t)tc * 64 + b) * 1024 + e0;
#pragma unroll
        for (int j = 0; j < 8; ++j) dst[j] = a[j] + red[eo * 8 + j];
    }
}

// reduce 16 partials -> applied (output 1, f32) at out+65536
__global__ __launch_bounds__(256) void applied_reduce_kernel(
    const float* __restrict__ part, float* __restrict__ out_applied)
{
    int idx = blockIdx.x * 256 + threadIdx.x;
    float s = 0.f;
#pragma unroll
    for (int tc = 0; tc < 16; ++tc) s += part[tc * 65536 + idx];
    out_applied[idx] = s;
}

// ---------------------------------------------------------------------------
// out[b,d] = tanh(dec[b].Wc[d,:1024] + applied[b].Wc[d,1024:] + bc[d])
// Register-tiled: each wave computes an 8d x 8b output tile, so each Wc /
// comb element loaded once serves 8 FMAs in registers. grid = 256 x 4 waves.
// ---------------------------------------------------------------------------
__global__ __launch_bounds__(256) void combine_kernel(
    const float* __restrict__ dec,       // [64,1024]
    const float* applied,                // [64,1024] (= out+65536)
    const float* __restrict__ Wc,        // [1024,2048]
    const float* __restrict__ bc,        // [1024]
    float* out0)                         // first 65536 of d_out
{
    const int gw   = blockIdx.x * 4 + (threadIdx.x >> 6);  // 0..1023
    const int lane = threadIdx.x & 63;
    const int d0   = (gw >> 3) * 8;      // 128 d-groups
    const int b0   = (gw & 7) * 8;       // 8 b-groups

    float acc[8][8];
#pragma unroll
    for (int dd = 0; dd < 8; ++dd)
#pragma unroll
        for (int bb = 0; bb < 8; ++bb) acc[dd][bb] = 0.f;

#pragma unroll
    for (int j = 0; j < 8; ++j) {
        float4 wv[8];
#pragma unroll
        for (int dd = 0; dd < 8; ++dd)
            wv[dd] = ((const float4*)(Wc + (size_t)(d0 + dd) * 2048))[j * 64 + lane];
        float4 cv[8];
        if (j < 4) {
#pragma unroll
            for (int bb = 0; bb < 8; ++bb)
                cv[bb] = ((const float4*)(dec + (size_t)(b0 + bb) * 1024))[j * 64 + lane];
        } else {
#pragma unroll
            for (int bb = 0; bb < 8; ++bb)
                cv[bb] = ((const float4*)(applied + (size_t)(b0 + bb) * 1024))[(j - 4) * 64 + lane];
        }
#pragma unroll
        for (int dd = 0; dd < 8; ++dd)
#pragma unroll
            for (int bb = 0; bb < 8; ++bb)
                acc[dd][bb] += wv[dd].x * cv[bb].x + wv[dd].y * cv[bb].y
                             + wv[dd].z * cv[bb].z + wv[dd].w * cv[bb].w;
    }

#pragma unroll
    for (int dd = 0; dd < 8; ++dd) {
#pragma unroll
        for (int bb = 0; bb < 8; ++bb) {
            float s = acc[dd][bb];
#pragma unroll
            for (int m = 32; m; m >>= 1) s += __shfl_xor(s, m);
            if (lane == 0)
                out0[(size_t)(b0 + bb) * DD + d0 + dd] = tanh_fast(s + bc[d0 + dd]);
        }
    }
}

// ---------------------------------------------------------------------------
extern "C" void kernel_launch(void* const* d_in, const int* in_sizes, int n_in,
                              void* d_out, int out_size, void* d_ws, size_t ws_size,
                              hipStream_t stream) {
    const float* hidden = (const float*)d_in[0]; // [64,1024]
    const float* dec    = (const float*)d_in[1]; // [64,1024]
    const float* enc    = (const float*)d_in[2]; // [512,64,1024]
    const float* Wa     = (const float*)d_in[3]; // [2048,2048]
    const float* ba     = (const float*)d_in[4]; // [2048]
    const float* w2     = (const float*)d_in[5]; // [2048]
    // d_in[6] = b2: uniform shift of scores -> softmax-invariant, unused.
    const float* Wc     = (const float*)d_in[7]; // [1024,2048]
    const float* bc     = (const float*)d_in[8]; // [1024]
    float* out = (float*)d_out;                  // [64*1024 out | 64*1024 applied]

    unsigned short* encS = (unsigned short*)d_ws;               // 33554432 bf16 (tiled)
    unsigned short* WaS  = encS + (size_t)33554432;             //  2097152 bf16 (tiled)
    float* hp     = (float*)(WaS + (size_t)2097152);            //   131072 f32
    float* scores = hp + 131072;                                //    32768 f32
    float* part   = scores + 32768;                             //  1048576 f32

    hipMemsetAsync(scores, 0, BB * TT * sizeof(float), stream);
    dim3 gc(256, 16);
    conv_encS_kernel<<<gc, 256, 0, stream>>>(enc, encS);
    dim3 gw(16, 16);
    conv_waS_kernel<<<gw, 256, 0, stream>>>(Wa, WaS);
    hproj_kernel<<<256, 256, 0, stream>>>(hidden, Wa, ba, hp);
    gemm_scores<<<1024, 512, 0, stream>>>(encS, WaS, hp, w2, scores);
    softmax_kernel<<<BB, 256, 0, stream>>>(scores);
    dim3 g3(16, 64);
    applied_part_kernel<<<g3, 256, 0, stream>>>(enc, scores, part);
    applied_reduce_kernel<<<256, 256, 0, stream>>>(part, out + BB * DD);
    combine_kernel<<<256, 256, 0, stream>>>(dec, out + BB * DD, Wc, bc, out);
}

// Round 6
// 540.774 us; speedup vs baseline: 1.1277x; 1.0767x over previous
//
#include <hip/hip_runtime.h>
#include <hip/hip_bf16.h>

// B=64 batch, T=512 enc timesteps, E=1024 enc hidden, D=1024 dec hidden
// ALL inputs/outputs are FLOAT32 (per reference setup_inputs).
#define BB 64
#define TT 512
#define EE 1024
#define DD 1024
// Fused e-proj GEMM: M = T*B = 32768, N = 2E = 2048, K = E = 1024 (bf16 MFMA)
#define BK 64   // k-tile depth

typedef __attribute__((ext_vector_type(8))) short s16x8;   // 8 bf16 MFMA A/B frag
typedef __attribute__((ext_vector_type(4))) float f32x4;   // MFMA C/D frag

#define AS1 __attribute__((address_space(1)))
#define AS3 __attribute__((address_space(3)))

__device__ __forceinline__ float bf2f(unsigned short u) {
    unsigned int x = ((unsigned int)u) << 16;
    return __builtin_bit_cast(float, x);
}
__device__ __forceinline__ unsigned short f2bf(float f) {   // RNE, finite inputs
    unsigned int u = __builtin_bit_cast(unsigned int, f);
    u += 0x7FFF + ((u >> 16) & 1);
    return (unsigned short)(u >> 16);
}
__device__ __forceinline__ float tanh_fast(float x) {
    x = fminf(fmaxf(x, -15.f), 15.f);
    float e = __expf(2.f * x);
    return (e - 1.f) / (e + 1.f);
}

// Tile-order slot for chunk (row 0..127, g 0..7):  [8 bf16 chunks of 16B]
//   slot = (row>>4)*128 + (g>>2)*64 + (g&3)*16 + (row&15)
// Fragment reads are lane-linear: slot = m16*128 + kk*64 + lane -> lane holds
//   A[row=m16*16+(lane&15)][k=kk*32+(lane>>4)*8 ..+8]
__device__ __forceinline__ int tile_slot(int row, int g) {
    return (row >> 4) * 128 + (g >> 2) * 64 + (g & 3) * 16 + (row & 15);
}

// ---------------------------------------------------------------------------
// enc f32 [32768,1024] -> encS bf16 tiled: tile (tm 0..255, tk 0..15) of
// 128 rows x 64 k stored as 1024 chunks in tile_slot order (16 KB/tile).
// grid = (256, 16), block = 256. LDS transpose for coalescing on both ends.
// ---------------------------------------------------------------------------
__global__ __launch_bounds__(256) void conv_encS_kernel(
    const float* __restrict__ enc, unsigned short* __restrict__ encS)
{
    __shared__ short tileL[1024 * 8];   // 16 KB
    const int tm  = blockIdx.x;
    const int tk  = blockIdx.y;
    const int tid = threadIdx.x;

#pragma unroll
    for (int it = 0; it < 4; ++it) {
        int cidx = it * 256 + tid;       // chunk id
        int row  = cidx >> 3;            // 0..127
        int g    = cidx & 7;             // 0..7
        const float* src = enc + (size_t)(tm * 128 + row) * 1024 + tk * 64 + g * 8;
        float4 v0 = ((const float4*)src)[0];
        float4 v1 = ((const float4*)src)[1];
        short c[8];
        c[0] = (short)f2bf(v0.x); c[1] = (short)f2bf(v0.y);
        c[2] = (short)f2bf(v0.z); c[3] = (short)f2bf(v0.w);
        c[4] = (short)f2bf(v1.x); c[5] = (short)f2bf(v1.y);
        c[6] = (short)f2bf(v1.z); c[7] = (short)f2bf(v1.w);
        *(s16x8*)&tileL[tile_slot(row, g) * 8] = *(s16x8*)c;
    }
    __syncthreads();
    unsigned short* dst = encS + ((size_t)tm * 16 + tk) * 8192;
#pragma unroll
    for (int it = 0; it < 4; ++it) {
        int s = it * 256 + tid;
        *(s16x8*)&dst[s * 8] = *(const s16x8*)&tileL[s * 8];
    }
}

// ---------------------------------------------------------------------------
// Wa[:,1024:2048] f32 -> WaS bf16 tiled: tile (tn 0..15, tk 0..15), same
// tile_slot order (rows = f within 128-col tile). grid = (16,16).
// ---------------------------------------------------------------------------
__global__ __launch_bounds__(256) void conv_waS_kernel(
    const float* __restrict__ Wa, unsigned short* __restrict__ WaS)
{
    __shared__ short tileL[1024 * 8];
    const int tn  = blockIdx.x;
    const int tk  = blockIdx.y;
    const int tid = threadIdx.x;

#pragma unroll
    for (int it = 0; it < 4; ++it) {
        int cidx = it * 256 + tid;
        int row  = cidx >> 3;            // f within tile
        int g    = cidx & 7;
        const float* src = Wa + (size_t)(tn * 128 + row) * 2048 + 1024 + tk * 64 + g * 8;
        float4 v0 = ((const float4*)src)[0];
        float4 v1 = ((const float4*)src)[1];
        short c[8];
        c[0] = (short)f2bf(v0.x); c[1] = (short)f2bf(v0.y);
        c[2] = (short)f2bf(v0.z); c[3] = (short)f2bf(v0.w);
        c[4] = (short)f2bf(v1.x); c[5] = (short)f2bf(v1.y);
        c[6] = (short)f2bf(v1.z); c[7] = (short)f2bf(v1.w);
        *(s16x8*)&tileL[tile_slot(row, g) * 8] = *(s16x8*)c;
    }
    __syncthreads();
    unsigned short* dst = WaS + ((size_t)tn * 16 + tk) * 8192;
#pragma unroll
    for (int it = 0; it < 4; ++it) {
        int s = it * 256 + tid;
        *(s16x8*)&dst[s * 8] = *(const s16x8*)&tileL[s * 8];
    }
}

// ---------------------------------------------------------------------------
// hproj[f][b] = hidden[b,:1024] . Wa[f,:1024] + ba[f]   (f-major, f32)
// ---------------------------------------------------------------------------
__global__ __launch_bounds__(256) void hproj_kernel(
    const float* __restrict__ hidden,   // [64,1024]
    const float* __restrict__ Wa,       // [2048,2048]
    const float* __restrict__ ba,       // [2048]
    float* __restrict__ hp)             // [2048*64]
{
    __shared__ float sW[8 * 1024];      // 32 KB
    const int tid  = threadIdx.x;
    const int lane = tid & 63;
    const int wave = tid >> 6;
    const int f0   = blockIdx.x * 8;

#pragma unroll
    for (int i = 0; i < 8; ++i) {
        int idx = i * 256 + tid;
        int fi  = idx >> 8;
        int c4  = idx & 255;
        ((float4*)sW)[idx] = *(const float4*)(Wa + (size_t)(f0 + fi) * 2048 + c4 * 4);
    }
    __syncthreads();

    for (int bi = 0; bi < 16; ++bi) {
        int b = wave * 16 + bi;
        float h[16];
#pragma unroll
        for (int j = 0; j < 16; ++j) h[j] = hidden[b * 1024 + lane + 64 * j];
#pragma unroll
        for (int fi = 0; fi < 8; ++fi) {
            float s = 0.f;
#pragma unroll
            for (int j = 0; j < 16; ++j) s += h[j] * sW[fi * 1024 + lane + 64 * j];
#pragma unroll
            for (int m = 32; m; m >>= 1) s += __shfl_xor(s, m);
            if (lane == 0) hp[(f0 + fi) * 64 + b] = s + ba[f0 + fi];
        }
    }
}

// ---------------------------------------------------------------------------
// Fused e_proj GEMM (bf16 MFMA) + tanh + w2-dot -> scores
// 256x256 tile, 8 waves (2M x 4N), BK=64. TWO-HALF schedule, 2 barriers
// per K-tile (was 6): each half = {counted vmcnt wait; s_barrier; issue 2
// stage pairs for kt+1; 16 ds_read + 32 MFMA in ONE free scheduling region}.
// The compiler interleaves lgkmcnt-counted ds_reads with MFMA, and the
// 2 waves/SIMD drift within the region to overlap reads vs MFMA.
// Wait counts (steady state, 8 loads/tile/wave, order B0,B1,A-h0,A-h1):
//   half0 top: in-flight = kt.B(4)+kt.A(4); need oldest 6 -> vmcnt(2)
//   half1 top: in-flight = kt.A-h1(2)+kt+1.B(4); need oldest 2 -> vmcnt(4)
// Main loop never drains to 0 (except final tile's half1).
// grid = 1024 (XCD-swizzled, bn-fast), block = 512.
// ---------------------------------------------------------------------------
__global__ __launch_bounds__(512, 2) void gemm_scores(
    const unsigned short* __restrict__ encS,  // tiled bf16 (ws), 256 x 16 tiles
    const unsigned short* __restrict__ WaS,   // tiled bf16 (ws), 16 x 16 tiles
    const float* __restrict__ hp,             // [2048*64] f32, f-major
    const float* __restrict__ w2,             // [2048] f32
    float* __restrict__ scores)               // [64*512] f32, zeroed
{
    __shared__ short sA[2][2][8192];   // [buf][mt] 16KB pre-swizzled tiles (64 KB)
    __shared__ short sB[2][2][8192];   // [buf][nt]                         (64 KB)
    __shared__ float rowAcc[256];

    const int tid  = threadIdx.x;
    // XCD-aware bijective swizzle: 1024 blocks, 8 XCDs, 128 w's each; bn-fast.
    const int bid  = blockIdx.x;
    const int w    = (bid & 7) * 128 + (bid >> 3);
    const int bm   = w >> 3;          // 0..127  (M/256)
    const int bn   = w & 7;           // 0..7    (N/256)
    const int lane = tid & 63;
    const int wave = tid >> 6;        // 0..7
    const int wm   = wave >> 2;       // 0..1  (M half)
    const int wn   = wave & 3;        // 0..3  (N quarter)
    const int c    = lane & 15;
    const int quad = lane >> 4;
    const int ntile = wn >> 1;          // which 128-col B tile this wave reads
    const int nrow0 = (wn & 1) * 4;     // f16-row base within that tile

    f32x4 acc[8][4];
#pragma unroll
    for (int m = 0; m < 8; ++m)
#pragma unroll
        for (int n = 0; n < 4; ++n)
#pragma unroll
            for (int r = 0; r < 4; ++r) acc[m][n][r] = 0.f;

    const unsigned short* aT = encS + ((size_t)(bm * 2) * 16) * 8192; // +(mt*16+kt)*8192
    const unsigned short* bT = WaS  + ((size_t)(bn * 2) * 16) * 8192; // +(nt*16+kt)*8192

    // Stage pair p for K-tile kt into buffer nb. ISSUE ORDER (per thread):
    //   p=0: B0 (both halves)   p=1: B1 (both halves)
    //   p=2: A0-h0, A1-h0       p=3: A0-h1, A1-h1
    auto STAGE_PAIR = [&](int kt, int nb, int p) {
        if (p < 2) {
            const unsigned short* src = bT + ((size_t)(p * 16 + kt)) * 8192;
            __builtin_amdgcn_global_load_lds(
                (const AS1 void*)(src + tid * 8),
                (AS3 void*)&sB[nb][p][tid * 8], 16, 0, 0);
            __builtin_amdgcn_global_load_lds(
                (const AS1 void*)(src + (512 + tid) * 8),
                (AS3 void*)&sB[nb][p][(512 + tid) * 8], 16, 0, 0);
        } else {
            const int h = (p - 2) * 512;   // half: slots 0-511 or 512-1023
            const unsigned short* s0 = aT + ((size_t)kt) * 8192;
            const unsigned short* s1 = aT + ((size_t)(16 + kt)) * 8192;
            __builtin_amdgcn_global_load_lds(
                (const AS1 void*)(s0 + (h + tid) * 8),
                (AS3 void*)&sA[nb][0][(h + tid) * 8], 16, 0, 0);
            __builtin_amdgcn_global_load_lds(
                (const AS1 void*)(s1 + (h + tid) * 8),
                (AS3 void*)&sA[nb][1][(h + tid) * 8], 16, 0, 0);
        }
    };

    // prologue: issue all 8 loads for tile 0 into buffer 0 (queue L0..L7)
#pragma unroll
    for (int p = 0; p < 4; ++p) STAGE_PAIR(0, 0, p);

    for (int kt = 0; kt < 16; ++kt) {
        const int cur = kt & 1;
        const bool pf = (kt < 15);

        // ================= half 0 : m = 0..3 =================
        // need kt.B(4) + kt.A-h0(2) = oldest 6; kt.A-h1(2) may stay in flight
        asm volatile("s_waitcnt vmcnt(2)" ::: "memory");
        __builtin_amdgcn_s_barrier();
        __builtin_amdgcn_sched_barrier(0);
        // all waves past tile kt-1 entirely -> buffer cur^1 readers done;
        // safe to overwrite with kt+1 data
        if (pf) { STAGE_PAIR(kt + 1, cur ^ 1, 0); STAGE_PAIR(kt + 1, cur ^ 1, 1); }

        s16x8 bF[2][4];   // [kk][n], live across both halves
#pragma unroll
        for (int n = 0; n < 4; ++n)
#pragma unroll
            for (int kk = 0; kk < 2; ++kk)
                bF[kk][n] = *(const s16x8*)
                    &sB[cur][ntile][((nrow0 + n) * 128 + kk * 64 + lane) * 8];
        {
            s16x8 aF[4][2];   // m = 0..3
#pragma unroll
            for (int m = 0; m < 4; ++m)
#pragma unroll
                for (int kk = 0; kk < 2; ++kk)
                    aF[m][kk] = *(const s16x8*)
                        &sA[cur][wm][(m * 128 + kk * 64 + lane) * 8];
            __builtin_amdgcn_s_setprio(1);
#pragma unroll
            for (int m = 0; m < 4; ++m)
#pragma unroll
                for (int kk = 0; kk < 2; ++kk)
#pragma unroll
                    for (int n = 0; n < 4; ++n)
                        acc[m][n] = __builtin_amdgcn_mfma_f32_16x16x32_bf16(
                            aF[m][kk], bF[kk][n], acc[m][n], 0, 0, 0);
            __builtin_amdgcn_s_setprio(0);
        }

        // ================= half 1 : m = 4..7 =================
        // need kt.A-h1(2) = oldest 2; kt+1.B(4) stays in flight
        if (pf) asm volatile("s_waitcnt vmcnt(4)" ::: "memory");
        else    asm volatile("s_waitcnt vmcnt(0)" ::: "memory");
        __builtin_amdgcn_s_barrier();
        __builtin_amdgcn_sched_barrier(0);
        if (pf) { STAGE_PAIR(kt + 1, cur ^ 1, 2); STAGE_PAIR(kt + 1, cur ^ 1, 3); }

        {
            s16x8 aF[4][2];   // m = 4..7
#pragma unroll
            for (int m = 0; m < 4; ++m)
#pragma unroll
                for (int kk = 0; kk < 2; ++kk)
                    aF[m][kk] = *(const s16x8*)
                        &sA[cur][wm][((m + 4) * 128 + kk * 64 + lane) * 8];
            __builtin_amdgcn_s_setprio(1);
#pragma unroll
            for (int m = 0; m < 4; ++m)
#pragma unroll
                for (int kk = 0; kk < 2; ++kk)
#pragma unroll
                    for (int n = 0; n < 4; ++n)
                        acc[m + 4][n] = __builtin_amdgcn_mfma_f32_16x16x32_bf16(
                            aF[m][kk], bF[kk][n], acc[m + 4][n], 0, 0, 0);
            __builtin_amdgcn_s_setprio(0);
        }
    }

    // Epilogue: scores_row += sum_f tanh(C + hp) * w2 over this block's 256 cols.
    __syncthreads();
    if (tid < 256) rowAcc[tid] = 0.f;
    __syncthreads();

    float w2v[4];
#pragma unroll
    for (int n = 0; n < 4; ++n) w2v[n] = w2[bn * 256 + wn * 64 + n * 16 + c];

#pragma unroll
    for (int m = 0; m < 8; ++m) {
        int lrow0 = wm * 128 + m * 16 + quad * 4;       // local row, 4-aligned
        int b0    = lrow0 & 63;                          // batch base (bm*256 % 64 == 0)
        f32x4 hp4[4];
#pragma unroll
        for (int n = 0; n < 4; ++n)
            hp4[n] = *(const f32x4*)&hp[(bn * 256 + wn * 64 + n * 16 + c) * 64 + b0];
#pragma unroll
        for (int r = 0; r < 4; ++r) {
            float s = 0.f;
#pragma unroll
            for (int n = 0; n < 4; ++n)
                s += tanh_fast(acc[m][n][r] + hp4[n][r]) * w2v[n];
            s += __shfl_xor(s, 1);
            s += __shfl_xor(s, 2);
            s += __shfl_xor(s, 4);
            s += __shfl_xor(s, 8);
            if (c == 0) atomicAdd(&rowAcc[lrow0 + r], s);
        }
    }
    __syncthreads();
    if (tid < 256) {
        int b = tid & 63;
        int t = bm * 4 + (tid >> 6);
        atomicAdd(&scores[b * TT + t], rowAcc[tid]);
    }
}

// ---------------------------------------------------------------------------
// Softmax over T per batch row, in-place on scores [64][512]
// ---------------------------------------------------------------------------
__global__ __launch_bounds__(256) void softmax_kernel(float* __restrict__ scores)
{
    __shared__ float wmax[4];
    __shared__ float wsum[4];
    const int b   = blockIdx.x;
    const int tid = threadIdx.x;
    float* row = scores + b * TT;

    float v0 = row[tid], v1 = row[tid + 256];
    float m = fmaxf(v0, v1);
#pragma unroll
    for (int s = 32; s; s >>= 1) m = fmaxf(m, __shfl_xor(m, s));
    if ((tid & 63) == 0) wmax[tid >> 6] = m;
    __syncthreads();
    m = fmaxf(fmaxf(wmax[0], wmax[1]), fmaxf(wmax[2], wmax[3]));

    float e0 = __expf(v0 - m), e1 = __expf(v1 - m);
    float s = e0 + e1;
#pragma unroll
    for (int t = 32; t; t >>= 1) s += __shfl_xor(s, t);
    if ((tid & 63) == 0) wsum[tid >> 6] = s;
    __syncthreads();
    float inv = 1.f / (wsum[0] + wsum[1] + wsum[2] + wsum[3]);
    row[tid]       = e0 * inv;
    row[tid + 256] = e1 * inv;
}

// ---------------------------------------------------------------------------
// applied partials from ORIGINAL f32 enc (coalesced 4KB rows):
// part[tc][b][e] = sum_{t in chunk tc} w[b,t]*enc[t,b,e]
// grid = (16 tc, 64 b), block = 256: 128 e-owners x 2 t-halves
// ---------------------------------------------------------------------------
__global__ __launch_bounds__(256) void applied_part_kernel(
    const float* __restrict__ enc,            // [T,B,E] f32
    const float* __restrict__ w,              // [64,512] weights
    float* __restrict__ part)                 // [16][64][1024]
{
    __shared__ float red[128 * 8];
    const int tc  = blockIdx.x;
    const int b   = blockIdx.y;
    const int tid = threadIdx.x;
    const int eo  = tid & 127;
    const int th  = tid >> 7;
    const int e0  = eo * 8;

    float a[8];
#pragma unroll
    for (int j = 0; j < 8; ++j) a[j] = 0.f;

    for (int it = 0; it < 16; ++it) {
        int t = tc * 32 + th * 16 + it;
        float wt = w[b * TT + t];
        const float* src = enc + ((size_t)(t * BB + b)) * EE + e0;
        float4 v0 = ((const float4*)src)[0];
        float4 v1 = ((const float4*)src)[1];
        a[0] += wt * v0.x; a[1] += wt * v0.y; a[2] += wt * v0.z; a[3] += wt * v0.w;
        a[4] += wt * v1.x; a[5] += wt * v1.y; a[6] += wt * v1.z; a[7] += wt * v1.w;
    }
    if (th == 1) {
#pragma unroll
        for (int j = 0; j < 8; ++j) red[eo * 8 + j] = a[j];
    }
    __syncthreads();
    if (th == 0) {
        float* dst = part + ((size_t)tc * 64 + b) * 1024 + e0;
#pragma unroll
        for (int j = 0; j < 8; ++j) dst[j] = a[j] + red[eo * 8 + j];
    }
}

// reduce 16 partials -> applied (output 1, f32) at out+65536
__global__ __launch_bounds__(256) void applied_reduce_kernel(
    const float* __restrict__ part, float* __restrict__ out_applied)
{
    int idx = blockIdx.x * 256 + threadIdx.x;
    float s = 0.f;
#pragma unroll
    for (int tc = 0; tc < 16; ++tc) s += part[tc * 65536 + idx];
    out_applied[idx] = s;
}

// ---------------------------------------------------------------------------
// out[b,d] = tanh(dec[b].Wc[d,:1024] + applied[b].Wc[d,1024:] + bc[d])
// Register-tiled: each wave computes a 4d x 8b output tile. 2048 waves
// (512 blocks x 4) = 2 waves/SIMD for latency hiding; Wc traffic 64 MB.
// ---------------------------------------------------------------------------
__global__ __launch_bounds__(256) void combine_kernel(
    const float* __restrict__ dec,       // [64,1024]
    const float* applied,                // [64,1024] (= out+65536)
    const float* __restrict__ Wc,        // [1024,2048]
    const float* __restrict__ bc,        // [1024]
    float* out0)                         // first 65536 of d_out
{
    const int gw   = blockIdx.x * 4 + (threadIdx.x >> 6);  // 0..2047
    const int lane = threadIdx.x & 63;
    const int d0   = (gw >> 3) * 4;      // 256 d-groups of 4 rows
    const int b0   = (gw & 7) * 8;       // 8 b-groups of 8 batches

    float acc[4][8];
#pragma unroll
    for (int dd = 0; dd < 4; ++dd)
#pragma unroll
        for (int bb = 0; bb < 8; ++bb) acc[dd][bb] = 0.f;

#pragma unroll
    for (int j = 0; j < 8; ++j) {
        float4 wv[4];
#pragma unroll
        for (int dd = 0; dd < 4; ++dd)
            wv[dd] = ((const float4*)(Wc + (size_t)(d0 + dd) * 2048))[j * 64 + lane];
        float4 cv[8];
        if (j < 4) {
#pragma unroll
            for (int bb = 0; bb < 8; ++bb)
                cv[bb] = ((const float4*)(dec + (size_t)(b0 + bb) * 1024))[j * 64 + lane];
        } else {
#pragma unroll
            for (int bb = 0; bb < 8; ++bb)
                cv[bb] = ((const float4*)(applied + (size_t)(b0 + bb) * 1024))[(j - 4) * 64 + lane];
        }
#pragma unroll
        for (int dd = 0; dd < 4; ++dd)
#pragma unroll
            for (int bb = 0; bb < 8; ++bb)
                acc[dd][bb] += wv[dd].x * cv[bb].x + wv[dd].y * cv[bb].y
                             + wv[dd].z * cv[bb].z + wv[dd].w * cv[bb].w;
    }

#pragma unroll
    for (int dd = 0; dd < 4; ++dd) {
#pragma unroll
        for (int bb = 0; bb < 8; ++bb) {
            float s = acc[dd][bb];
#pragma unroll
            for (int m = 32; m; m >>= 1) s += __shfl_xor(s, m);
            if (lane == 0)
                out0[(size_t)(b0 + bb) * DD + d0 + dd] = tanh_fast(s + bc[d0 + dd]);
        }
    }
}

// ---------------------------------------------------------------------------
extern "C" void kernel_launch(void* const* d_in, const int* in_sizes, int n_in,
                              void* d_out, int out_size, void* d_ws, size_t ws_size,
                              hipStream_t stream) {
    const float* hidden = (const float*)d_in[0]; // [64,1024]
    const float* dec    = (const float*)d_in[1]; // [64,1024]
    const float* enc    = (const float*)d_in[2]; // [512,64,1024]
    const float* Wa     = (const float*)d_in[3]; // [2048,2048]
    const float* ba     = (const float*)d_in[4]; // [2048]
    const float* w2     = (const float*)d_in[5]; // [2048]
    // d_in[6] = b2: uniform shift of scores -> softmax-invariant, unused.
    const float* Wc     = (const float*)d_in[7]; // [1024,2048]
    const float* bc     = (const float*)d_in[8]; // [1024]
    float* out = (float*)d_out;                  // [64*1024 out | 64*1024 applied]

    unsigned short* encS = (unsigned short*)d_ws;               // 33554432 bf16 (tiled)
    unsigned short* WaS  = encS + (size_t)33554432;             //  2097152 bf16 (tiled)
    float* hp     = (float*)(WaS + (size_t)2097152);            //   131072 f32
    float* scores = hp + 131072;                                //    32768 f32
    float* part   = scores + 32768;                             //  1048576 f32

    hipMemsetAsync(scores, 0, BB * TT * sizeof(float), stream);
    dim3 gc(256, 16);
    conv_encS_kernel<<<gc, 256, 0, stream>>>(enc, encS);
    dim3 gw(16, 16);
    conv_waS_kernel<<<gw, 256, 0, stream>>>(Wa, WaS);
    hproj_kernel<<<256, 256, 0, stream>>>(hidden, Wa, ba, hp);
    gemm_scores<<<1024, 512, 0, stream>>>(encS, WaS, hp, w2, scores);
    softmax_kernel<<<BB, 256, 0, stream>>>(scores);
    dim3 g3(16, 64);
    applied_part_kernel<<<g3, 256, 0, stream>>>(enc, scores, part);
    applied_reduce_kernel<<<256, 256, 0, stream>>>(part, out + BB * DD);
    combine_kernel<<<512, 256, 0, stream>>>(dec, out + BB * DD, Wc, bc, out);
}

// Round 7
// 511.790 us; speedup vs baseline: 1.1916x; 1.0566x over previous
//
#include <hip/hip_runtime.h>
#include <hip/hip_bf16.h>

// B=64 batch, T=512 enc timesteps, E=1024 enc hidden, D=1024 dec hidden
// ALL inputs/outputs are FLOAT32 (per reference setup_inputs).
#define BB 64
#define TT 512
#define EE 1024
#define DD 1024
// Fused e-proj GEMM: M = T*B = 32768, N = 2E = 2048, K = E = 1024 (bf16 MFMA)
#define BK 64   // k-tile depth

typedef __attribute__((ext_vector_type(8))) short s16x8;   // 8 bf16 MFMA A/B frag
typedef __attribute__((ext_vector_type(4))) float f32x4;   // MFMA C/D frag

#define AS1 __attribute__((address_space(1)))
#define AS3 __attribute__((address_space(3)))

__device__ __forceinline__ float bf2f(unsigned short u) {
    unsigned int x = ((unsigned int)u) << 16;
    return __builtin_bit_cast(float, x);
}
__device__ __forceinline__ unsigned short f2bf(float f) {   // RNE, finite inputs
    unsigned int u = __builtin_bit_cast(unsigned int, f);
    u += 0x7FFF + ((u >> 16) & 1);
    return (unsigned short)(u >> 16);
}
__device__ __forceinline__ float tanh_fast(float x) {
    x = fminf(fmaxf(x, -15.f), 15.f);
    float e = __expf(2.f * x);
    return (e - 1.f) / (e + 1.f);
}

// Tile-order slot for chunk (row 0..127, g 0..7):  [8 bf16 chunks of 16B]
//   slot = (row>>4)*128 + (g>>2)*64 + (g&3)*16 + (row&15)
// Fragment reads are lane-linear: slot = m16*128 + kk*64 + lane -> lane holds
//   A[row=m16*16+(lane&15)][k=kk*32+(lane>>4)*8 ..+8]
__device__ __forceinline__ int tile_slot(int row, int g) {
    return (row >> 4) * 128 + (g >> 2) * 64 + (g & 3) * 16 + (row & 15);
}

// ---------------------------------------------------------------------------
// enc f32 [32768,1024] -> encS bf16 tiled: tile (tm 0..255, tk 0..15) of
// 128 rows x 64 k stored as 1024 chunks in tile_slot order (16 KB/tile).
// grid = (256, 16), block = 256. LDS transpose for coalescing on both ends.
// ---------------------------------------------------------------------------
__global__ __launch_bounds__(256) void conv_encS_kernel(
    const float* __restrict__ enc, unsigned short* __restrict__ encS)
{
    __shared__ short tileL[1024 * 8];   // 16 KB
    const int tm  = blockIdx.x;
    const int tk  = blockIdx.y;
    const int tid = threadIdx.x;

#pragma unroll
    for (int it = 0; it < 4; ++it) {
        int cidx = it * 256 + tid;       // chunk id
        int row  = cidx >> 3;            // 0..127
        int g    = cidx & 7;             // 0..7
        const float* src = enc + (size_t)(tm * 128 + row) * 1024 + tk * 64 + g * 8;
        float4 v0 = ((const float4*)src)[0];
        float4 v1 = ((const float4*)src)[1];
        short c[8];
        c[0] = (short)f2bf(v0.x); c[1] = (short)f2bf(v0.y);
        c[2] = (short)f2bf(v0.z); c[3] = (short)f2bf(v0.w);
        c[4] = (short)f2bf(v1.x); c[5] = (short)f2bf(v1.y);
        c[6] = (short)f2bf(v1.z); c[7] = (short)f2bf(v1.w);
        *(s16x8*)&tileL[tile_slot(row, g) * 8] = *(s16x8*)c;
    }
    __syncthreads();
    unsigned short* dst = encS + ((size_t)tm * 16 + tk) * 8192;
#pragma unroll
    for (int it = 0; it < 4; ++it) {
        int s = it * 256 + tid;
        *(s16x8*)&dst[s * 8] = *(const s16x8*)&tileL[s * 8];
    }
}

// ---------------------------------------------------------------------------
// Wa[:,1024:2048] f32 -> WaS bf16 tiled: tile (tn 0..15, tk 0..15), same
// tile_slot order (rows = f within 128-col tile). grid = (16,16).
// ---------------------------------------------------------------------------
__global__ __launch_bounds__(256) void conv_waS_kernel(
    const float* __restrict__ Wa, unsigned short* __restrict__ WaS)
{
    __shared__ short tileL[1024 * 8];
    const int tn  = blockIdx.x;
    const int tk  = blockIdx.y;
    const int tid = threadIdx.x;

#pragma unroll
    for (int it = 0; it < 4; ++it) {
        int cidx = it * 256 + tid;
        int row  = cidx >> 3;            // f within tile
        int g    = cidx & 7;
        const float* src = Wa + (size_t)(tn * 128 + row) * 2048 + 1024 + tk * 64 + g * 8;
        float4 v0 = ((const float4*)src)[0];
        float4 v1 = ((const float4*)src)[1];
        short c[8];
        c[0] = (short)f2bf(v0.x); c[1] = (short)f2bf(v0.y);
        c[2] = (short)f2bf(v0.z); c[3] = (short)f2bf(v0.w);
        c[4] = (short)f2bf(v1.x); c[5] = (short)f2bf(v1.y);
        c[6] = (short)f2bf(v1.z); c[7] = (short)f2bf(v1.w);
        *(s16x8*)&tileL[tile_slot(row, g) * 8] = *(s16x8*)c;
    }
    __syncthreads();
    unsigned short* dst = WaS + ((size_t)tn * 16 + tk) * 8192;
#pragma unroll
    for (int it = 0; it < 4; ++it) {
        int s = it * 256 + tid;
        *(s16x8*)&dst[s * 8] = *(const s16x8*)&tileL[s * 8];
    }
}

// ---------------------------------------------------------------------------
// hproj[f][b] = hidden[b,:1024] . Wa[f,:1024] + ba[f]   (f-major, f32)
// ---------------------------------------------------------------------------
__global__ __launch_bounds__(256) void hproj_kernel(
    const float* __restrict__ hidden,   // [64,1024]
    const float* __restrict__ Wa,       // [2048,2048]
    const float* __restrict__ ba,       // [2048]
    float* __restrict__ hp)             // [2048*64]
{
    __shared__ float sW[8 * 1024];      // 32 KB
    const int tid  = threadIdx.x;
    const int lane = tid & 63;
    const int wave = tid >> 6;
    const int f0   = blockIdx.x * 8;

#pragma unroll
    for (int i = 0; i < 8; ++i) {
        int idx = i * 256 + tid;
        int fi  = idx >> 8;
        int c4  = idx & 255;
        ((float4*)sW)[idx] = *(const float4*)(Wa + (size_t)(f0 + fi) * 2048 + c4 * 4);
    }
    __syncthreads();

    for (int bi = 0; bi < 16; ++bi) {
        int b = wave * 16 + bi;
        float h[16];
#pragma unroll
        for (int j = 0; j < 16; ++j) h[j] = hidden[b * 1024 + lane + 64 * j];
#pragma unroll
        for (int fi = 0; fi < 8; ++fi) {
            float s = 0.f;
#pragma unroll
            for (int j = 0; j < 16; ++j) s += h[j] * sW[fi * 1024 + lane + 64 * j];
#pragma unroll
            for (int m = 32; m; m >>= 1) s += __shfl_xor(s, m);
            if (lane == 0) hp[(f0 + fi) * 64 + b] = s + ba[f0 + fi];
        }
    }
}

// ---------------------------------------------------------------------------
// Fused e_proj GEMM (bf16 MFMA) + tanh + w2-dot -> scores
// 256x256 tile, **16 waves** (4M x 4N, 64x64 output each, 1024 threads).
// Rationale: the 8-wave variants carried 128 acc regs + ~108 VGPR = 236/wave
// -> hard 2 waves/SIMD; every stall was exposed. 16x(64x64) needs only
// 64 acc + ~56 operand/addr regs < 128 -> 4 waves/SIMD; stalls overlap
// across waves (m114 mechanism). Double-buffered LDS, 4 stage loads/thread
// per K-tile issued right after the tile-top barrier (full-tile cover for
// the next tile's vmcnt(0)).
// grid = 1024 (XCD-swizzled, bn-fast), block = 1024.
// ---------------------------------------------------------------------------
__global__ __launch_bounds__(1024) void gemm_scores(
    const unsigned short* __restrict__ encS,  // tiled bf16 (ws), 256 x 16 tiles
    const unsigned short* __restrict__ WaS,   // tiled bf16 (ws), 16 x 16 tiles
    const float* __restrict__ hp,             // [2048*64] f32, f-major
    const float* __restrict__ w2,             // [2048] f32
    float* __restrict__ scores)               // [64*512] f32, zeroed
{
    __shared__ short sA[2][2][8192];   // [buf][mt] 16KB pre-swizzled tiles (64 KB)
    __shared__ short sB[2][2][8192];   // [buf][nt]                         (64 KB)
    __shared__ float rowAcc[256];

    const int tid  = threadIdx.x;
    // XCD-aware bijective swizzle: 1024 blocks, 8 XCDs, 128 w's each; bn-fast.
    const int bid  = blockIdx.x;
    const int w    = (bid & 7) * 128 + (bid >> 3);
    const int bm   = w >> 3;          // 0..127  (M/256)
    const int bn   = w & 7;           // 0..7    (N/256)
    const int lane = tid & 63;
    const int wave = tid >> 6;        // 0..15
    const int wm   = wave >> 2;       // 0..3  (M quarter)
    const int wn   = wave & 3;        // 0..3  (N quarter)
    const int c    = lane & 15;
    const int quad = lane >> 4;
    const int mt   = wm >> 1;           // A LDS tile for this wave
    const int mrow0 = (wm & 1) * 4;     // m16-row base within that tile
    const int nt   = wn >> 1;           // B LDS tile
    const int nrow0 = (wn & 1) * 4;

    f32x4 acc[4][4];
#pragma unroll
    for (int m = 0; m < 4; ++m)
#pragma unroll
        for (int n = 0; n < 4; ++n)
#pragma unroll
            for (int r = 0; r < 4; ++r) acc[m][n][r] = 0.f;

    const unsigned short* aT = encS + ((size_t)(bm * 2) * 16) * 8192; // +(mt*16+kt)*8192
    const unsigned short* bT = WaS  + ((size_t)(bn * 2) * 16) * 8192; // +(nt*16+kt)*8192

    // Stage ALL 4 tiles (A0,A1,B0,B1) for K-tile kt into buffer nb:
    // 1024 threads x 1 chunk per tile = 4 global_load_lds per thread.
    auto STAGE_ALL = [&](int kt, int nb) {
#pragma unroll
        for (int t = 0; t < 2; ++t) {
            const unsigned short* sa = aT + ((size_t)(t * 16 + kt)) * 8192;
            __builtin_amdgcn_global_load_lds(
                (const AS1 void*)(sa + tid * 8),
                (AS3 void*)&sA[nb][t][tid * 8], 16, 0, 0);
            const unsigned short* sb = bT + ((size_t)(t * 16 + kt)) * 8192;
            __builtin_amdgcn_global_load_lds(
                (const AS1 void*)(sb + tid * 8),
                (AS3 void*)&sB[nb][t][tid * 8], 16, 0, 0);
        }
    };

    // prologue: fill buffer 0
    STAGE_ALL(0, 0);

    for (int kt = 0; kt < 16; ++kt) {
        const int cur = kt & 1;
        // wait own 4 loads for tile kt (issued one full K-tile ago -> covered)
        asm volatile("s_waitcnt vmcnt(0)" ::: "memory");
        __builtin_amdgcn_s_barrier();
        __builtin_amdgcn_sched_barrier(0);
        if (kt < 15) STAGE_ALL(kt + 1, cur ^ 1);   // flies under this tile's compute

#pragma unroll
        for (int kk = 0; kk < 2; ++kk) {
            s16x8 aF[4], bF[4];
#pragma unroll
            for (int m = 0; m < 4; ++m)
                aF[m] = *(const s16x8*)
                    &sA[cur][mt][((mrow0 + m) * 128 + kk * 64 + lane) * 8];
#pragma unroll
            for (int n = 0; n < 4; ++n)
                bF[n] = *(const s16x8*)
                    &sB[cur][nt][((nrow0 + n) * 128 + kk * 64 + lane) * 8];

            __builtin_amdgcn_s_setprio(1);
#pragma unroll
            for (int m = 0; m < 4; ++m)
#pragma unroll
                for (int n = 0; n < 4; ++n)
                    acc[m][n] = __builtin_amdgcn_mfma_f32_16x16x32_bf16(
                        aF[m], bF[n], acc[m][n], 0, 0, 0);
            __builtin_amdgcn_s_setprio(0);
        }
        __builtin_amdgcn_sched_barrier(0);
        __builtin_amdgcn_s_barrier();   // all reads of buf cur done before overwrite
    }

    // Epilogue: scores_row += sum_f tanh(C + hp) * w2 over this block's 256 cols.
    if (tid < 256) rowAcc[tid] = 0.f;
    __syncthreads();

    float w2v[4];
#pragma unroll
    for (int n = 0; n < 4; ++n) w2v[n] = w2[bn * 256 + wn * 64 + n * 16 + c];

#pragma unroll
    for (int m = 0; m < 4; ++m) {
        int lrow0 = wm * 64 + m * 16 + quad * 4;        // local row, 4-aligned
        int b0    = lrow0 & 63;                          // batch base (bm*256 % 64 == 0)
        f32x4 hp4[4];
#pragma unroll
        for (int n = 0; n < 4; ++n)
            hp4[n] = *(const f32x4*)&hp[(bn * 256 + wn * 64 + n * 16 + c) * 64 + b0];
#pragma unroll
        for (int r = 0; r < 4; ++r) {
            float s = 0.f;
#pragma unroll
            for (int n = 0; n < 4; ++n)
                s += tanh_fast(acc[m][n][r] + hp4[n][r]) * w2v[n];
            s += __shfl_xor(s, 1);
            s += __shfl_xor(s, 2);
            s += __shfl_xor(s, 4);
            s += __shfl_xor(s, 8);
            if (c == 0) atomicAdd(&rowAcc[lrow0 + r], s);
        }
    }
    __syncthreads();
    if (tid < 256) {
        int b = tid & 63;
        int t = bm * 4 + (tid >> 6);
        atomicAdd(&scores[b * TT + t], rowAcc[tid]);
    }
}

// ---------------------------------------------------------------------------
// Softmax over T per batch row, in-place on scores [64][512]
// ---------------------------------------------------------------------------
__global__ __launch_bounds__(256) void softmax_kernel(float* __restrict__ scores)
{
    __shared__ float wmax[4];
    __shared__ float wsum[4];
    const int b   = blockIdx.x;
    const int tid = threadIdx.x;
    float* row = scores + b * TT;

    float v0 = row[tid], v1 = row[tid + 256];
    float m = fmaxf(v0, v1);
#pragma unroll
    for (int s = 32; s; s >>= 1) m = fmaxf(m, __shfl_xor(m, s));
    if ((tid & 63) == 0) wmax[tid >> 6] = m;
    __syncthreads();
    m = fmaxf(fmaxf(wmax[0], wmax[1]), fmaxf(wmax[2], wmax[3]));

    float e0 = __expf(v0 - m), e1 = __expf(v1 - m);
    float s = e0 + e1;
#pragma unroll
    for (int t = 32; t; t >>= 1) s += __shfl_xor(s, t);
    if ((tid & 63) == 0) wsum[tid >> 6] = s;
    __syncthreads();
    float inv = 1.f / (wsum[0] + wsum[1] + wsum[2] + wsum[3]);
    row[tid]       = e0 * inv;
    row[tid + 256] = e1 * inv;
}

// ---------------------------------------------------------------------------
// applied partials from ORIGINAL f32 enc (coalesced 4KB rows):
// part[tc][b][e] = sum_{t in chunk tc} w[b,t]*enc[t,b,e]
// grid = (16 tc, 64 b), block = 256: 128 e-owners x 2 t-halves
// ---------------------------------------------------------------------------
__global__ __launch_bounds__(256) void applied_part_kernel(
    const float* __restrict__ enc,            // [T,B,E] f32
    const float* __restrict__ w,              // [64,512] weights
    float* __restrict__ part)                 // [16][64][1024]
{
    __shared__ float red[128 * 8];
    const int tc  = blockIdx.x;
    const int b   = blockIdx.y;
    const int tid = threadIdx.x;
    const int eo  = tid & 127;
    const int th  = tid >> 7;
    const int e0  = eo * 8;

    float a[8];
#pragma unroll
    for (int j = 0; j < 8; ++j) a[j] = 0.f;

    for (int it = 0; it < 16; ++it) {
        int t = tc * 32 + th * 16 + it;
        float wt = w[b * TT + t];
        const float* src = enc + ((size_t)(t * BB + b)) * EE + e0;
        float4 v0 = ((const float4*)src)[0];
        float4 v1 = ((const float4*)src)[1];
        a[0] += wt * v0.x; a[1] += wt * v0.y; a[2] += wt * v0.z; a[3] += wt * v0.w;
        a[4] += wt * v1.x; a[5] += wt * v1.y; a[6] += wt * v1.z; a[7] += wt * v1.w;
    }
    if (th == 1) {
#pragma unroll
        for (int j = 0; j < 8; ++j) red[eo * 8 + j] = a[j];
    }
    __syncthreads();
    if (th == 0) {
        float* dst = part + ((size_t)tc * 64 + b) * 1024 + e0;
#pragma unroll
        for (int j = 0; j < 8; ++j) dst[j] = a[j] + red[eo * 8 + j];
    }
}

// reduce 16 partials -> applied (output 1, f32) at out+65536
__global__ __launch_bounds__(256) void applied_reduce_kernel(
    const float* __restrict__ part, float* __restrict__ out_applied)
{
    int idx = blockIdx.x * 256 + threadIdx.x;
    float s = 0.f;
#pragma unroll
    for (int tc = 0; tc < 16; ++tc) s += part[tc * 65536 + idx];
    out_applied[idx] = s;
}

// ---------------------------------------------------------------------------
// out[b,d] = tanh(dec[b].Wc[d,:1024] + applied[b].Wc[d,1024:] + bc[d])
// Register-tiled: each wave computes an 8d x 8b output tile (round-3 best).
// grid = 256 blocks x 4 waves.
// ---------------------------------------------------------------------------
__global__ __launch_bounds__(256) void combine_kernel(
    const float* __restrict__ dec,       // [64,1024]
    const float* applied,                // [64,1024] (= out+65536)
    const float* __restrict__ Wc,        // [1024,2048]
    const float* __restrict__ bc,        // [1024]
    float* out0)                         // first 65536 of d_out
{
    const int gw   = blockIdx.x * 4 + (threadIdx.x >> 6);  // 0..1023
    const int lane = threadIdx.x & 63;
    const int d0   = (gw >> 3) * 8;      // 128 d-groups
    const int b0   = (gw & 7) * 8;       // 8 b-groups

    float acc[8][8];
#pragma unroll
    for (int dd = 0; dd < 8; ++dd)
#pragma unroll
        for (int bb = 0; bb < 8; ++bb) acc[dd][bb] = 0.f;

#pragma unroll
    for (int j = 0; j < 8; ++j) {
        float4 wv[8];
#pragma unroll
        for (int dd = 0; dd < 8; ++dd)
            wv[dd] = ((const float4*)(Wc + (size_t)(d0 + dd) * 2048))[j * 64 + lane];
        float4 cv[8];
        if (j < 4) {
#pragma unroll
            for (int bb = 0; bb < 8; ++bb)
                cv[bb] = ((const float4*)(dec + (size_t)(b0 + bb) * 1024))[j * 64 + lane];
        } else {
#pragma unroll
            for (int bb = 0; bb < 8; ++bb)
                cv[bb] = ((const float4*)(applied + (size_t)(b0 + bb) * 1024))[(j - 4) * 64 + lane];
        }
#pragma unroll
        for (int dd = 0; dd < 8; ++dd)
#pragma unroll
            for (int bb = 0; bb < 8; ++bb)
                acc[dd][bb] += wv[dd].x * cv[bb].x + wv[dd].y * cv[bb].y
                             + wv[dd].z * cv[bb].z + wv[dd].w * cv[bb].w;
    }

#pragma unroll
    for (int dd = 0; dd < 8; ++dd) {
#pragma unroll
        for (int bb = 0; bb < 8; ++bb) {
            float s = acc[dd][bb];
#pragma unroll
            for (int m = 32; m; m >>= 1) s += __shfl_xor(s, m);
            if (lane == 0)
                out0[(size_t)(b0 + bb) * DD + d0 + dd] = tanh_fast(s + bc[d0 + dd]);
        }
    }
}

// ---------------------------------------------------------------------------
extern "C" void kernel_launch(void* const* d_in, const int* in_sizes, int n_in,
                              void* d_out, int out_size, void* d_ws, size_t ws_size,
                              hipStream_t stream) {
    const float* hidden = (const float*)d_in[0]; // [64,1024]
    const float* dec    = (const float*)d_in[1]; // [64,1024]
    const float* enc    = (const float*)d_in[2]; // [512,64,1024]
    const float* Wa     = (const float*)d_in[3]; // [2048,2048]
    const float* ba     = (const float*)d_in[4]; // [2048]
    const float* w2     = (const float*)d_in[5]; // [2048]
    // d_in[6] = b2: uniform shift of scores -> softmax-invariant, unused.
    const float* Wc     = (const float*)d_in[7]; // [1024,2048]
    const float* bc     = (const float*)d_in[8]; // [1024]
    float* out = (float*)d_out;                  // [64*1024 out | 64*1024 applied]

    unsigned short* encS = (unsigned short*)d_ws;               // 33554432 bf16 (tiled)
    unsigned short* WaS  = encS + (size_t)33554432;             //  2097152 bf16 (tiled)
    float* hp     = (float*)(WaS + (size_t)2097152);            //   131072 f32
    float* scores = hp + 131072;                                //    32768 f32
    float* part   = scores + 32768;                             //  1048576 f32

    hipMemsetAsync(scores, 0, BB * TT * sizeof(float), stream);
    dim3 gc(256, 16);
    conv_encS_kernel<<<gc, 256, 0, stream>>>(enc, encS);
    dim3 gw(16, 16);
    conv_waS_kernel<<<gw, 256, 0, stream>>>(Wa, WaS);
    hproj_kernel<<<256, 256, 0, stream>>>(hidden, Wa, ba, hp);
    gemm_scores<<<1024, 1024, 0, stream>>>(encS, WaS, hp, w2, scores);
    softmax_kernel<<<BB, 256, 0, stream>>>(scores);
    dim3 g3(16, 64);
    applied_part_kernel<<<g3, 256, 0, stream>>>(enc, scores, part);
    applied_reduce_kernel<<<256, 256, 0, stream>>>(part, out + BB * DD);
    combine_kernel<<<256, 256, 0, stream>>>(dec, out + BB * DD, Wc, bc, out);
}